// Round 6
// baseline (9862.755 us; speedup 1.0000x reference)
//
#include <hip/hip_runtime.h>
#include <stdint.h>

// B=4, S=2048, D=1024, H=16, HD=64.
// Inputs fp32 (proven R1-R5). OUTPUT fp32 — "d_out holds the reference's
// OUTPUT dtype"; reference returns fp32. Rounds 1-5 wrote bf16 into a float*
// buffer: explains the bit-identical 1.98 absmax across three different
// implementations (permuted halves + zero tail). This round: fp32 everywhere.
#define B_ 4
#define S_ 2048
#define D_ 1024
#define H_ 16
#define HD_ 64

typedef float f32x4 __attribute__((ext_vector_type(4)));

// Diagnostic channel: absmax ≈ sentinel when a host-fact assumption fails.
__global__ void write_sentinel(float* __restrict__ out, float v) {
  if (threadIdx.x == 0 && blockIdx.x == 0) out[0] = v;
}

// ---------------------------------------------------------------------------
// QKV GEMM (fp32): qkv[m][j] = sum_k hidden[a_off + m*1024 + k] * W[k][gn] + b[gn]
// where gn = sec*1024 + hbase*64 + within maps local col j (sections q|k|v of
// Hg*64 cols) to the global 3072-wide weight column. Hg=16,hbase=0 → identity.
// Block (16,16), each thread 4 consecutive cols (f32x4 W loads, coalesced).
// ---------------------------------------------------------------------------
__global__ __launch_bounds__(256) void gemm_qkv(
    const float* __restrict__ A, size_t a_off, const float* __restrict__ W,
    const float* __restrict__ bias, float* __restrict__ Cq, int Hg, int hbase) {
  const int tx = threadIdx.x, ty = threadIdx.y;  // 16 x 16
  const int m = blockIdx.y * 16 + ty;            // row in [0, 2048)
  const int secSize = Hg * 64;
  const int j = blockIdx.x * 64 + tx * 4;        // local col in [0, 3*secSize)
  const int sec = j / secSize;
  const int within = j - sec * secSize;
  const int gn = sec * 1024 + hbase * 64 + within;

  const float* a = A + a_off + (size_t)m * 1024;
  const float* wp = W + gn;
  float a0 = 0.f, a1 = 0.f, a2 = 0.f, a3 = 0.f;
#pragma unroll 4
  for (int k = 0; k < 1024; ++k) {
    float av = a[k];  // broadcast across tx (same row) — L1 hit
    f32x4 w = *(const f32x4*)(wp + (size_t)k * 3072);
    a0 += av * w[0];
    a1 += av * w[1];
    a2 += av * w[2];
    a3 += av * w[3];
  }
  float* cp = Cq + (size_t)m * (3 * secSize) + j;
  cp[0] = a0 + bias[gn + 0];
  cp[1] = a1 + bias[gn + 1];
  cp[2] = a2 + bias[gn + 2];
  cp[3] = a3 + bias[gn + 3];
}

// ---------------------------------------------------------------------------
// Naive causal attention (fp32). One wave per (q row, local head).
// qkv: [S][3*Hg*64] (q|k|v sections). aws: [S][1024], head col (hbase+h)*64.
// Two-pass softmax, scale 1/sqrt(64)=0.125.
// ---------------------------------------------------------------------------
__global__ __launch_bounds__(256) void attn_f32(
    const float* __restrict__ qkv, int Hg, int hbase, float* __restrict__ aws) {
  __shared__ float Ss[4][S_];  // 32 KB
  __shared__ float Qs[4][64];
  const int tid = threadIdx.x;
  const int w = tid >> 6, lane = tid & 63;
  const int h = blockIdx.y;           // local head [0, Hg)
  const int q = blockIdx.x * 4 + w;   // query row
  const int secSize = Hg * 64;
  const int ncols = 3 * secSize;

  Qs[w][lane] = qkv[(size_t)q * ncols + h * 64 + lane];
  __syncthreads();

  // pass 1: scores + max
  float mx = -1e30f;
  for (int key = lane; key <= q; key += 64) {
    const float* kp = qkv + (size_t)key * ncols + secSize + h * 64;
    float s = 0.f;
#pragma unroll 8
    for (int d = 0; d < 64; ++d) s += Qs[w][d] * kp[d];
    s *= 0.125f;
    Ss[w][key] = s;
    mx = fmaxf(mx, s);
  }
#pragma unroll
  for (int off = 32; off >= 1; off >>= 1)
    mx = fmaxf(mx, __shfl_xor(mx, off, 64));
  __syncthreads();

  // pass 2: exp + denom
  float l = 0.f;
  for (int key = lane; key <= q; key += 64) {
    float p = expf(Ss[w][key] - mx);
    Ss[w][key] = p;
    l += p;
  }
#pragma unroll
  for (int off = 32; off >= 1; off >>= 1) l += __shfl_xor(l, off, 64);
  __syncthreads();

  // pass 3: P @ V (lane = hd, coalesced 256B per key, V slab L2-resident)
  float acc = 0.f;
  const float* vp = qkv + 2 * secSize + h * 64 + lane;
  for (int key = 0; key <= q; ++key) acc += Ss[w][key] * vp[(size_t)key * ncols];

  aws[(size_t)q * D_ + (hbase + h) * 64 + lane] = acc / l;
}

// ---------------------------------------------------------------------------
// Projection GEMM (fp32): out[m][j] = sum_k aws[m][k] * Wp[k][j] + bp[j]
// ---------------------------------------------------------------------------
__global__ __launch_bounds__(256) void gemm_proj(
    const float* __restrict__ Aws, const float* __restrict__ W,
    const float* __restrict__ bias, float* __restrict__ Cout) {
  const int tx = threadIdx.x, ty = threadIdx.y;  // 16 x 16
  const int m = blockIdx.y * 16 + ty;
  const int j = blockIdx.x * 64 + tx * 4;
  const float* a = Aws + (size_t)m * 1024;
  const float* wp = W + j;
  float a0 = 0.f, a1 = 0.f, a2 = 0.f, a3 = 0.f;
#pragma unroll 4
  for (int k = 0; k < 1024; ++k) {
    float av = a[k];
    f32x4 w = *(const f32x4*)(wp + (size_t)k * 1024);
    a0 += av * w[0];
    a1 += av * w[1];
    a2 += av * w[2];
    a3 += av * w[3];
  }
  float* cp = Cout + (size_t)m * 1024 + j;
  cp[0] = a0 + bias[j + 0];
  cp[1] = a1 + bias[j + 1];
  cp[2] = a2 + bias[j + 2];
  cp[3] = a3 + bias[j + 3];
}

// ---------------------------------------------------------------------------
extern "C" void kernel_launch(void* const* d_in, const int* in_sizes, int n_in,
                              void* d_out, int out_size, void* d_ws,
                              size_t ws_size, hipStream_t stream) {
  float* out = (float*)d_out;

  // --- host-fact verification (all host-visible; sentinel-encode violations)
  const float* hidden = nullptr;  // 8,388,608
  const float* attn_w = nullptr;  // 3,145,728
  const float* attn_b = nullptr;  //     3,072
  const float* proj_w = nullptr;  // 1,048,576
  const float* proj_b = nullptr;  //     1,024
  for (int i = 0; i < n_in; ++i) {
    switch (in_sizes[i]) {
      case 8388608: hidden = (const float*)d_in[i]; break;
      case 3145728: attn_w = (const float*)d_in[i]; break;
      case 3072:    attn_b = (const float*)d_in[i]; break;
      case 1048576: proj_w = (const float*)d_in[i]; break;
      case 1024:    proj_b = (const float*)d_in[i]; break;
      default: break;
    }
  }
  if (!hidden || !attn_w || !attn_b || !proj_w || !proj_b) {
    write_sentinel<<<1, 64, 0, stream>>>(out, 3000.0f + (float)n_in);
    return;
  }
  if (out_size != 8388608) {
    write_sentinel<<<1, 64, 0, stream>>>(
        out, 7000.0f + (float)(out_size / 1048576));
    return;
  }

  char* ws = (char*)d_ws;
  const size_t AWS_B = (size_t)S_ * D_ * 4;        //  8.39 MB
  const size_t QKV_FULL_B = (size_t)S_ * 3072 * 4; // 25.17 MB
  const size_t QKV_HG_B = (size_t)S_ * 768 * 4;    //  6.29 MB

  if (ws_size >= AWS_B + QKV_FULL_B) {  // 33.6 MB: full-width per-batch
    float* aws = (float*)ws;
    float* qkv = (float*)(ws + AWS_B);
    for (int b = 0; b < B_; ++b) {
      gemm_qkv<<<dim3(48, 128), dim3(16, 16), 0, stream>>>(
          hidden, (size_t)b * S_ * D_, attn_w, attn_b, qkv, 16, 0);
      attn_f32<<<dim3(512, 16), 256, 0, stream>>>(qkv, 16, 0, aws);
      gemm_proj<<<dim3(16, 128), dim3(16, 16), 0, stream>>>(
          aws, proj_w, proj_b, out + (size_t)b * S_ * D_);
    }
  } else if (ws_size >= AWS_B + QKV_HG_B) {  // 14.7 MB: per-4-head groups
    float* aws = (float*)ws;
    float* qkv = (float*)(ws + AWS_B);
    for (int b = 0; b < B_; ++b) {
      for (int hg = 0; hg < 4; ++hg) {
        gemm_qkv<<<dim3(12, 128), dim3(16, 16), 0, stream>>>(
            hidden, (size_t)b * S_ * D_, attn_w, attn_b, qkv, 4, hg * 4);
        attn_f32<<<dim3(512, 4), 256, 0, stream>>>(qkv, 4, hg * 4, aws);
      }
      gemm_proj<<<dim3(16, 128), dim3(16, 16), 0, stream>>>(
          aws, proj_w, proj_b, out + (size_t)b * S_ * D_);
    }
  } else {
    write_sentinel<<<1, 64, 0, stream>>>(
        out, 5000.0f + (float)(ws_size / 1048576));
  }
}

// Round 7
// 596.462 us; speedup vs baseline: 16.5354x; 16.5354x over previous
//
#include <hip/hip_runtime.h>
#include <hip/hip_bf16.h>
#include <stdint.h>

// B=4, S=2048, D=1024, H=16, HD=64.
// Inputs fp32, OUTPUT fp32 (R6-proven). Intermediates bf16; MFMA pipeline
// (R3/R4 structure — function-equivalence to the naive R5/R6 pipeline was
// proven by bit-identical outputs; only the final store dtype was wrong).
#define B_ 4
#define S_ 2048
#define D_ 1024
#define H_ 16
#define HD_ 64

typedef __bf16 bf16_t;
typedef bf16_t bf16x8 __attribute__((ext_vector_type(8)));
typedef float f32x4 __attribute__((ext_vector_type(4)));

__device__ __forceinline__ bf16x8 cvt8(f32x4 lo, f32x4 hi) {
  bf16x8 r;
#pragma unroll
  for (int i = 0; i < 4; i++) {
    r[i] = (bf16_t)lo[i];
    r[i + 4] = (bf16_t)hi[i];
  }
  return r;
}

// ---------------------------------------------------------------------------
// GEMM: acc[m][n] = sum_k A[m][k] * W[k][n] + bias[n].
// A: [M][K] fp32 (a_is_f32=1, QKV) or bf16 (=0, proj), element offset a_off.
// W: [K][Nw] fp32 natural layout, transposed into LDS during staging.
// 128x128 tile, BK=32, 4 waves (2x2), each 64x64 via 4x4 MFMA 16x16x32.
// mode 0: store fp32 Cout[m][n] row-major (proj; grid.x = Nw/128).
// mode 1: QKV scatter into bf16 q/k/v [bb][H][S][HD] (Nw=3072, grid.x=24).
// mode 2: QKV head-group slice hg (grid.x=6; local heads 0..3).
// ---------------------------------------------------------------------------
__global__ __launch_bounds__(256) void gemm_fused(
    const void* __restrict__ A, const float* __restrict__ W,
    const float* __restrict__ bias, float* __restrict__ Cout,
    bf16_t* __restrict__ qws, bf16_t* __restrict__ kws,
    bf16_t* __restrict__ vws, int M, int Nw, int K, int mode, int hg,
    int a_is_f32, size_t a_off) {
  __shared__ bf16_t As[128 * 32];  // [m][k]
  __shared__ bf16_t Bs[128 * 40];  // [n][k], stride 40 elems (80B, 16B-mult)
  const int tid = threadIdx.x;
  const int wave = tid >> 6, lane = tid & 63;
  const int quad = lane >> 4, tn = lane & 15;
  const int m_blk = blockIdx.y * 128;
  const int wm = (wave >> 1) * 64, wn = (wave & 1) * 64;

  int col0, sec2 = 0;
  if (mode == 2) {
    sec2 = blockIdx.x >> 1;  // 0=q,1=k,2=v
    col0 = sec2 * 1024 + hg * 256 + (blockIdx.x & 1) * 128;
  } else {
    col0 = blockIdx.x * 128;
  }

  f32x4 acc[4][4] = {};

  // A staging: 16 rows x 32 cols per wave-instr; 2 instrs = 32 rows/wave
  const int srow = wave * 32 + (lane >> 2);
  const int scol = (lane & 3) * 8;
  size_t aoff = a_off + (size_t)(m_blk + srow) * K + scol;

  // W staging: thread k=tid>>3 (0..31), n chunk (tid&7)*16
  const int bk = tid >> 3;
  const int bn = (tid & 7) * 16;
  const float* gw = W + (size_t)bk * Nw + col0 + bn;

  for (int k0 = 0; k0 < K; k0 += 32) {
    bf16x8 a0, a1;
    if (a_is_f32) {
      const float* gaf = (const float*)A + aoff;
      a0 = cvt8(*(const f32x4*)gaf, *(const f32x4*)(gaf + 4));
      a1 = cvt8(*(const f32x4*)(gaf + (size_t)16 * K),
                *(const f32x4*)(gaf + (size_t)16 * K + 4));
    } else {
      const bf16_t* ga = (const bf16_t*)A + aoff;
      a0 = *(const bf16x8*)ga;
      a1 = *(const bf16x8*)(ga + (size_t)16 * K);
    }
    f32x4 w0 = *(const f32x4*)gw;
    f32x4 w1 = *(const f32x4*)(gw + 4);
    f32x4 w2 = *(const f32x4*)(gw + 8);
    f32x4 w3 = *(const f32x4*)(gw + 12);
    aoff += 32;
    gw += (size_t)32 * Nw;
    __syncthreads();  // previous iteration's LDS reads complete
    *(bf16x8*)&As[srow * 32 + scol] = a0;
    *(bf16x8*)&As[(srow + 16) * 32 + scol] = a1;
#pragma unroll
    for (int j = 0; j < 4; j++) {
      Bs[(bn + j) * 40 + bk] = (bf16_t)w0[j];
      Bs[(bn + 4 + j) * 40 + bk] = (bf16_t)w1[j];
      Bs[(bn + 8 + j) * 40 + bk] = (bf16_t)w2[j];
      Bs[(bn + 12 + j) * 40 + bk] = (bf16_t)w3[j];
    }
    __syncthreads();

    bf16x8 af[4], bfr[4];
#pragma unroll
    for (int i = 0; i < 4; i++)
      af[i] = *(const bf16x8*)&As[(wm + i * 16 + tn) * 32 + quad * 8];
#pragma unroll
    for (int i = 0; i < 4; i++)
      bfr[i] = *(const bf16x8*)&Bs[(wn + i * 16 + tn) * 40 + quad * 8];
#pragma unroll
    for (int mi = 0; mi < 4; mi++)
#pragma unroll
      for (int ni = 0; ni < 4; ni++)
        acc[mi][ni] = __builtin_amdgcn_mfma_f32_16x16x32_bf16(af[mi], bfr[ni],
                                                              acc[mi][ni], 0, 0, 0);
  }

  // Epilogue. C/D: col(n)=lane&15, row(m)=quad*4+r  [m89-verified]
  if (mode == 0) {  // fp32 store (final output)
#pragma unroll
    for (int ni = 0; ni < 4; ni++) {
      int n = col0 + wn + ni * 16 + tn;
      float bv = bias[n];
#pragma unroll
      for (int mi = 0; mi < 4; mi++)
#pragma unroll
        for (int r = 0; r < 4; r++) {
          int m = m_blk + wm + mi * 16 + quad * 4 + r;
          Cout[(size_t)m * Nw + n] = acc[mi][ni][r] + bv;
        }
    }
  } else if (mode == 1) {
#pragma unroll
    for (int ni = 0; ni < 4; ni++) {
      int n = col0 + wn + ni * 16 + tn;
      int sec = n >> 10;
      int hn = n & 1023;
      int h = hn >> 6, hd = hn & 63;
      bf16_t* dst = (sec == 0) ? qws : ((sec == 1) ? kws : vws);
      float bv = bias[n];
#pragma unroll
      for (int mi = 0; mi < 4; mi++)
#pragma unroll
        for (int r = 0; r < 4; r++) {
          int m = m_blk + wm + mi * 16 + quad * 4 + r;
          int bb = m >> 11, s = m & 2047;
          dst[((size_t)(bb * H_ + h) * S_ + s) * HD_ + hd] =
              (bf16_t)(acc[mi][ni][r] + bv);
        }
    }
  } else {  // mode 2: head-group slice, M=2048, local heads 0..3
#pragma unroll
    for (int ni = 0; ni < 4; ni++) {
      int nf = wn + ni * 16 + tn;               // 0..127 within block
      int n_loc = (blockIdx.x & 1) * 128 + nf;  // 0..255 within hg
      int h_loc = n_loc >> 6, hd = n_loc & 63;
      bf16_t* dst = (sec2 == 0) ? qws : ((sec2 == 1) ? kws : vws);
      float bv = bias[col0 + nf];
#pragma unroll
      for (int mi = 0; mi < 4; mi++)
#pragma unroll
        for (int r = 0; r < 4; r++) {
          int s = m_blk + wm + mi * 16 + quad * 4 + r;
          dst[((size_t)h_loc * S_ + s) * HD_ + hd] =
              (bf16_t)(acc[mi][ni][r] + bv);
        }
    }
  }
}

// ---------------------------------------------------------------------------
// Causal flash attention. Q/K/V: [nheads][S][64] bf16 (GEMM output).
// bh_base + blockIdx.y -> global (b,h) for merged-head bf16 output aws.
// 128 q/block (4 waves x 32 rows), 64-key tiles, online softmax (log2-domain),
// all-finite arithmetic. P round-trips LDS (m120-verified transform).
// ---------------------------------------------------------------------------
__global__ __launch_bounds__(256) void attn_kernel(
    const bf16_t* __restrict__ Qw, const bf16_t* __restrict__ Kw,
    const bf16_t* __restrict__ Vw, bf16_t* __restrict__ Ow, int bh_base) {
  __shared__ bf16_t Ks[64 * 72];     // [key][hd]
  __shared__ bf16_t Vt[64 * 72];     // [hd][key]
  __shared__ bf16_t Ps[4][32 * 72];  // per-wave P round-trip [q][key]

  const int tid = threadIdx.x;
  const int wave = tid >> 6, lane = tid & 63;
  const int quad = lane >> 4, tn = lane & 15;
  const int bh_l = blockIdx.y;
  const int qb = blockIdx.x * 128;
  const int wq = qb + wave * 32;

  const bf16_t* Qb = Qw + (size_t)bh_l * S_ * HD_;
  const bf16_t* Kb = Kw + (size_t)bh_l * S_ * HD_;
  const bf16_t* Vb = Vw + (size_t)bh_l * S_ * HD_;

  // Q fragments: A-layout m=lane&15, k=quad*8+j  [m120-verified]
  bf16x8 qf[2][2];
#pragma unroll
  for (int mi = 0; mi < 2; mi++)
#pragma unroll
    for (int ks = 0; ks < 2; ks++)
      qf[mi][ks] = *(const bf16x8*)&Qb[(size_t)(wq + mi * 16 + tn) * HD_ +
                                       ks * 32 + quad * 8];

  f32x4 o[2][4] = {};
  const float NEG = -30000.0f;
  float mrow[2][4], lrow[2][4];
#pragma unroll
  for (int mi = 0; mi < 2; mi++)
#pragma unroll
    for (int r = 0; r < 4; r++) {
      mrow[mi][r] = NEG;
      lrow[mi][r] = 0.f;
    }

  const float kScale = 0.125f * 1.44269504088896f;  // 1/sqrt(64) * log2(e)

  const int kt_max = (qb + 127) >> 6;                  // inclusive
  const int s_r = tid >> 2, s_c = (tid & 3) * 16;      // K stage mapping
  const int v_key = tid & 63, v_hb = (tid >> 6) * 16;  // V stage mapping

  for (int kt = 0; kt <= kt_max; kt++) {
    {  // stage K tile [64][hd] and V^T tile [hd][key]
      const bf16_t* kg = Kb + (size_t)(kt * 64 + s_r) * HD_ + s_c;
      *(bf16x8*)&Ks[s_r * 72 + s_c] = *(const bf16x8*)kg;
      *(bf16x8*)&Ks[s_r * 72 + s_c + 8] = *(const bf16x8*)(kg + 8);
      const bf16_t* vg = Vb + (size_t)(kt * 64 + v_key) * HD_ + v_hb;
      bf16x8 v0 = *(const bf16x8*)vg;
      bf16x8 v1 = *(const bf16x8*)(vg + 8);
#pragma unroll
      for (int j = 0; j < 8; j++) {
        Vt[(v_hb + j) * 72 + v_key] = v0[j];
        Vt[(v_hb + 8 + j) * 72 + v_key] = v1[j];
      }
    }
    __syncthreads();

    if (kt * 64 <= wq + 31) {  // wave-uniform; body has no barriers
      f32x4 s[2][4] = {};
#pragma unroll
      for (int ni = 0; ni < 4; ni++)
#pragma unroll
        for (int ks = 0; ks < 2; ks++) {
          bf16x8 kf = *(const bf16x8*)&Ks[(ni * 16 + tn) * 72 + ks * 32 + quad * 8];
#pragma unroll
          for (int mi = 0; mi < 2; mi++)
            s[mi][ni] = __builtin_amdgcn_mfma_f32_16x16x32_bf16(qf[mi][ks], kf,
                                                                s[mi][ni], 0, 0, 0);
        }
#pragma unroll
      for (int mi = 0; mi < 2; mi++)
#pragma unroll
        for (int ni = 0; ni < 4; ni++) {
          int key = kt * 64 + ni * 16 + tn;
#pragma unroll
          for (int r = 0; r < 4; r++) {
            int q = wq + mi * 16 + quad * 4 + r;
            float v = s[mi][ni][r] * kScale;
            s[mi][ni][r] = (key <= q) ? v : NEG;
          }
        }
#pragma unroll
      for (int mi = 0; mi < 2; mi++)
#pragma unroll
        for (int r = 0; r < 4; r++) {
          float mx = fmaxf(fmaxf(s[mi][0][r], s[mi][1][r]),
                           fmaxf(s[mi][2][r], s[mi][3][r]));
#pragma unroll
          for (int off = 1; off < 16; off <<= 1)
            mx = fmaxf(mx, __shfl_xor(mx, off, 64));
          float mnew = fmaxf(mrow[mi][r], mx);
          float alpha = exp2f(mrow[mi][r] - mnew);
          mrow[mi][r] = mnew;
          float rs = 0.f;
#pragma unroll
          for (int ni = 0; ni < 4; ni++) {
            float p = exp2f(s[mi][ni][r] - mnew);
            s[mi][ni][r] = p;
            rs += p;
          }
#pragma unroll
          for (int off = 1; off < 16; off <<= 1) rs += __shfl_xor(rs, off, 64);
          lrow[mi][r] = lrow[mi][r] * alpha + rs;
#pragma unroll
          for (int ni = 0; ni < 4; ni++) o[mi][ni][r] *= alpha;
        }
      // P: C-layout regs -> LDS [q][key], re-read as A-fragments
      bf16_t* Pw = Ps[wave];
#pragma unroll
      for (int mi = 0; mi < 2; mi++)
#pragma unroll
        for (int ni = 0; ni < 4; ni++)
#pragma unroll
          for (int r = 0; r < 4; r++)
            Pw[(mi * 16 + quad * 4 + r) * 72 + ni * 16 + tn] =
                (bf16_t)s[mi][ni][r];
#pragma unroll
      for (int ks = 0; ks < 2; ks++) {
        bf16x8 ap[2];
#pragma unroll
        for (int mi = 0; mi < 2; mi++)
          ap[mi] = *(const bf16x8*)&Pw[(mi * 16 + tn) * 72 + ks * 32 + quad * 8];
#pragma unroll
        for (int ni = 0; ni < 4; ni++) {
          bf16x8 vf = *(const bf16x8*)&Vt[(ni * 16 + tn) * 72 + ks * 32 + quad * 8];
#pragma unroll
          for (int mi = 0; mi < 2; mi++)
            o[mi][ni] = __builtin_amdgcn_mfma_f32_16x16x32_bf16(ap[mi], vf,
                                                                o[mi][ni], 0, 0, 0);
        }
      }
    }
    __syncthreads();
  }

  // normalize + store merged heads [b][s][h*64+hd] (bf16)
  const int bh_g = bh_base + bh_l;
  const int b = bh_g >> 4, h = bh_g & 15;
#pragma unroll
  for (int mi = 0; mi < 2; mi++)
#pragma unroll
    for (int r = 0; r < 4; r++) {
      int q = wq + mi * 16 + quad * 4 + r;
      float inv = 1.f / fmaxf(lrow[mi][r], 1e-30f);
      bf16_t* dst = Ow + ((size_t)(b * S_ + q) * D_) + h * HD_;
#pragma unroll
      for (int ni = 0; ni < 4; ni++)
        dst[ni * 16 + tn] = (bf16_t)(o[mi][ni][r] * inv);
    }
}

// ---------------------------------------------------------------------------
extern "C" void kernel_launch(void* const* d_in, const int* in_sizes, int n_in,
                              void* d_out, int out_size, void* d_ws,
                              size_t ws_size, hipStream_t stream) {
  // Inputs resolved by size (proven robust in R5/R6).
  const float* hidden = nullptr;
  const float* attn_w = nullptr;
  const float* attn_b = nullptr;
  const float* proj_w = nullptr;
  const float* proj_b = nullptr;
  for (int i = 0; i < n_in; ++i) {
    switch (in_sizes[i]) {
      case 8388608: hidden = (const float*)d_in[i]; break;
      case 3145728: attn_w = (const float*)d_in[i]; break;
      case 3072:    attn_b = (const float*)d_in[i]; break;
      case 1048576: proj_w = (const float*)d_in[i]; break;
      case 1024:    proj_b = (const float*)d_in[i]; break;
      default: break;
    }
  }
  if (!hidden) hidden = (const float*)d_in[0];
  if (!attn_w) attn_w = (const float*)d_in[1];
  if (!attn_b) attn_b = (const float*)d_in[2];
  if (!proj_w) proj_w = (const float*)d_in[3];
  if (!proj_b) proj_b = (const float*)d_in[4];
  float* out = (float*)d_out;  // [4,2048,1024] fp32

  char* ws = (char*)d_ws;
  const size_t AWS_FULL_B = (size_t)B_ * S_ * D_ * 2;    // 16.8 MB bf16
  const size_t AWS_B1_B = (size_t)S_ * D_ * 2;           //  4.2 MB
  const size_t QKV_FULL_E = (size_t)B_ * H_ * S_ * HD_;  // elems
  const size_t QKV_B1_E = (size_t)H_ * S_ * HD_;
  const size_t QKV_HG_E = (size_t)4 * S_ * HD_;
  const size_t NEED_A = AWS_FULL_B + 3 * QKV_FULL_E * 2;  // 67.1 MB
  const size_t NEED_B = AWS_B1_B + 3 * QKV_B1_E * 2;      // 16.8 MB

  if (ws_size >= NEED_A) {
    // Tier A: full pipeline, 3 launches.
    bf16_t* aws = (bf16_t*)ws;
    bf16_t* qws = (bf16_t*)(ws + AWS_FULL_B);
    bf16_t* kws = qws + QKV_FULL_E;
    bf16_t* vws = kws + QKV_FULL_E;
    gemm_fused<<<dim3(24, 64), 256, 0, stream>>>(
        hidden, attn_w, attn_b, nullptr, qws, kws, vws,
        8192, 3072, 1024, 1, 0, 1, 0);
    attn_kernel<<<dim3(16, 64), 256, 0, stream>>>(qws, kws, vws, aws, 0);
    gemm_fused<<<dim3(8, 64), 256, 0, stream>>>(
        aws, proj_w, proj_b, out, nullptr, nullptr, nullptr,
        8192, 1024, 1024, 0, 0, 0, 0);
  } else if (ws_size >= NEED_B) {
    // Tier B: per-batch pipeline (16.8 MB), 12 launches.
    bf16_t* awsb = (bf16_t*)ws;
    bf16_t* qws = (bf16_t*)(ws + AWS_B1_B);
    bf16_t* kws = qws + QKV_B1_E;
    bf16_t* vws = kws + QKV_B1_E;
    for (int b = 0; b < B_; b++) {
      gemm_fused<<<dim3(24, 16), 256, 0, stream>>>(
          hidden, attn_w, attn_b, nullptr, qws, kws, vws,
          2048, 3072, 1024, 1, 0, 1, (size_t)b * S_ * D_);
      attn_kernel<<<dim3(16, 16), 256, 0, stream>>>(qws, kws, vws, awsb, 0);
      gemm_fused<<<dim3(8, 16), 256, 0, stream>>>(
          awsb, proj_w, proj_b, out + (size_t)b * S_ * D_,
          nullptr, nullptr, nullptr, 2048, 1024, 1024, 0, 0, 0, 0);
    }
  } else {
    // Tier C: per-batch, per-head-group (7.3 MB), 36 launches.
    bf16_t* awsb = (bf16_t*)ws;
    bf16_t* qws = (bf16_t*)(ws + AWS_B1_B);
    bf16_t* kws = qws + QKV_HG_E;
    bf16_t* vws = kws + QKV_HG_E;
    for (int b = 0; b < B_; b++) {
      for (int hg = 0; hg < 4; hg++) {
        gemm_fused<<<dim3(6, 16), 256, 0, stream>>>(
            hidden, attn_w, attn_b, nullptr, qws, kws, vws,
            2048, 3072, 1024, 2, hg, 1, (size_t)b * S_ * D_);
        attn_kernel<<<dim3(16, 4), 256, 0, stream>>>(qws, kws, vws, awsb,
                                                     hg * 4);
      }
      gemm_fused<<<dim3(8, 16), 256, 0, stream>>>(
          awsb, proj_w, proj_b, out + (size_t)b * S_ * D_,
          nullptr, nullptr, nullptr, 2048, 1024, 1024, 0, 0, 0, 0);
    }
  }
}

// Round 8
// 492.673 us; speedup vs baseline: 20.0189x; 1.2107x over previous
//
#include <hip/hip_runtime.h>
#include <hip/hip_bf16.h>
#include <stdint.h>

// B=4, S=2048, D=1024, H=16, HD=64. Inputs fp32, OUTPUT fp32 (R6/R7-proven).
// Intermediates bf16. Workspace = exactly 64 MiB (proven available in R7):
//   aws  [0, 16.8MB)   bf16 [B*S][D]   (wT1 overlays; dead before attn)
//   qkv  [16.8, 67.1MB) bf16 q|k|v each [B,H,S,HD]
//   wT2 overlays qws, written AFTER attn consumed Q.
#define B_ 4
#define S_ 2048
#define D_ 1024
#define H_ 16
#define HD_ 64

typedef __bf16 bf16_t;
typedef bf16_t bf16x8 __attribute__((ext_vector_type(8)));
typedef float f32x4 __attribute__((ext_vector_type(4)));

__device__ __forceinline__ bf16x8 cvt8(f32x4 lo, f32x4 hi) {
  bf16x8 r;
#pragma unroll
  for (int i = 0; i < 4; i++) {
    r[i] = (bf16_t)lo[i];
    r[i + 4] = (bf16_t)hi[i];
  }
  return r;
}

// Async global->LDS, 16B/lane; LDS dest = wave-uniform base + lane*16.
__device__ __forceinline__ void async_lds16(const bf16_t* g, bf16_t* l) {
  __builtin_amdgcn_global_load_lds(
      (const __attribute__((address_space(1))) void*)g,
      (__attribute__((address_space(3))) void*)l, 16, 0, 0);
}

// ---------------------------------------------------------------------------
// Weight cvt+transpose: in fp32 [R][C] -> out bf16 [C][R].
// ---------------------------------------------------------------------------
__global__ void transpose_cvt(const float* __restrict__ in,
                              bf16_t* __restrict__ out, int R, int C) {
  __shared__ bf16_t tile[32][33];
  int c0 = blockIdx.x * 32, r0 = blockIdx.y * 32;
  int tx = threadIdx.x, ty = threadIdx.y;  // 32 x 8
  for (int i = ty; i < 32; i += 8)
    tile[i][tx] = (bf16_t)in[(size_t)(r0 + i) * C + c0 + tx];
  __syncthreads();
  for (int i = ty; i < 32; i += 8)
    out[(size_t)(c0 + i) * R + r0 + tx] = tile[tx][i];
}

// ---------------------------------------------------------------------------
// GEMM (m97 structure): C[m,n] = sum_k A[m,k]*BT[n,k] + bias[n].
// BT: bf16 [N][K] (pre-transposed) — staged via global_load_lds width-16.
// A: fp32 (a_is_f32=1: manual cvt staging) or bf16 (=0: async staging).
// 128x128 tile, BK=32, 4 waves (2x2), 4x4 MFMA 16x16x32 per wave.
// mode 0: fp32 store C[m][n] (final output). mode 1: QKV scatter (bf16).
// ---------------------------------------------------------------------------
__global__ __launch_bounds__(256) void gemm_bt(
    const void* __restrict__ A, const bf16_t* __restrict__ BT,
    const float* __restrict__ bias, float* __restrict__ Cout,
    bf16_t* __restrict__ qws, bf16_t* __restrict__ kws,
    bf16_t* __restrict__ vws, int M, int Nw, int K, int mode, int a_is_f32,
    size_t a_off) {
  __shared__ bf16_t As[128 * 32];  // [m][k] — contiguous (async-compatible)
  __shared__ bf16_t Bs[128 * 32];  // [n][k]
  const int tid = threadIdx.x;
  const int wave = tid >> 6, lane = tid & 63;
  const int quad = lane >> 4, tn = lane & 15;
  const int m_blk = blockIdx.y * 128, n_blk = blockIdx.x * 128;
  const int wm = (wave >> 1) * 64, wn = (wave & 1) * 64;

  f32x4 acc[4][4] = {};

  const int srow = wave * 32 + (lane >> 2);  // staged tile row
  const int scol = (lane & 3) * 8;           // staged k-offset (8 elems, 16B)
  size_t aoff = a_off + (size_t)(m_blk + srow) * K + scol;
  const bf16_t* gb = BT + (size_t)(n_blk + srow) * K + scol;
  bf16_t* lbB0 = &Bs[wave * 1024];
  bf16_t* lbB1 = &Bs[wave * 1024 + 512];
  bf16_t* laA0 = &As[wave * 1024];
  bf16_t* laA1 = &As[wave * 1024 + 512];

  for (int k0 = 0; k0 < K; k0 += 32) {
    // end-of-prev-iter barrier guarantees all LDS reads done before any write
    async_lds16(gb, lbB0);
    async_lds16(gb + (size_t)16 * K, lbB1);
    if (a_is_f32) {
      const float* gaf = (const float*)A + aoff;
      f32x4 a00 = *(const f32x4*)gaf;
      f32x4 a01 = *(const f32x4*)(gaf + 4);
      f32x4 a10 = *(const f32x4*)(gaf + (size_t)16 * K);
      f32x4 a11 = *(const f32x4*)(gaf + (size_t)16 * K + 4);
      *(bf16x8*)&As[srow * 32 + scol] = cvt8(a00, a01);
      *(bf16x8*)&As[(srow + 16) * 32 + scol] = cvt8(a10, a11);
    } else {
      const bf16_t* ga = (const bf16_t*)A + aoff;
      async_lds16(ga, laA0);
      async_lds16(ga + (size_t)16 * K, laA1);
    }
    aoff += 32;
    gb += 32;
    __syncthreads();  // drains vmcnt (async) + lgkm (manual A), joins waves

    bf16x8 af[4], bfr[4];
#pragma unroll
    for (int i = 0; i < 4; i++)
      af[i] = *(const bf16x8*)&As[(wm + i * 16 + tn) * 32 + quad * 8];
#pragma unroll
    for (int i = 0; i < 4; i++)
      bfr[i] = *(const bf16x8*)&Bs[(wn + i * 16 + tn) * 32 + quad * 8];
#pragma unroll
    for (int mi = 0; mi < 4; mi++)
#pragma unroll
      for (int ni = 0; ni < 4; ni++)
        acc[mi][ni] = __builtin_amdgcn_mfma_f32_16x16x32_bf16(af[mi], bfr[ni],
                                                              acc[mi][ni], 0, 0, 0);
    __syncthreads();  // all reads complete before next iteration's writes
  }

  // Epilogue. C/D: col(n)=lane&15, row(m)=quad*4+r  [m89-verified]
  if (mode == 0) {  // fp32 final store
#pragma unroll
    for (int ni = 0; ni < 4; ni++) {
      int n = n_blk + wn + ni * 16 + tn;
      float bv = bias[n];
#pragma unroll
      for (int mi = 0; mi < 4; mi++)
#pragma unroll
        for (int r = 0; r < 4; r++) {
          int m = m_blk + wm + mi * 16 + quad * 4 + r;
          Cout[(size_t)m * Nw + n] = acc[mi][ni][r] + bv;
        }
    }
  } else {  // QKV scatter into bf16 [bb][H][S][HD] chunks
#pragma unroll
    for (int ni = 0; ni < 4; ni++) {
      int n = n_blk + wn + ni * 16 + tn;
      int sec = n >> 10;
      int hn = n & 1023;
      int h = hn >> 6, hd = hn & 63;
      bf16_t* dst = (sec == 0) ? qws : ((sec == 1) ? kws : vws);
      float bv = bias[n];
#pragma unroll
      for (int mi = 0; mi < 4; mi++)
#pragma unroll
        for (int r = 0; r < 4; r++) {
          int m = m_blk + wm + mi * 16 + quad * 4 + r;
          int bb = m >> 11, s = m & 2047;
          dst[((size_t)(bb * H_ + h) * S_ + s) * HD_ + hd] =
              (bf16_t)(acc[mi][ni][r] + bv);
        }
    }
  }
}

// ---------------------------------------------------------------------------
// Causal flash attention. Q/K/V: [B*H][S][64] bf16. Out aws: [B,S,D] bf16.
// 128 q/block (4 waves x 32 rows), 64-key tiles, online softmax (log2 dom).
// R8: descending q-tile order (long blocks first), scale folded into Q
// fragments, mask skipped on fully-unmasked tiles.
// ---------------------------------------------------------------------------
__global__ __launch_bounds__(256) void attn_kernel(
    const bf16_t* __restrict__ Qw, const bf16_t* __restrict__ Kw,
    const bf16_t* __restrict__ Vw, bf16_t* __restrict__ Ow) {
  __shared__ bf16_t Ks[64 * 72];     // [key][hd]
  __shared__ bf16_t Vt[64 * 72];     // [hd][key]
  __shared__ bf16_t Ps[4][32 * 72];  // per-wave P round-trip [q][key]

  const int tid = threadIdx.x;
  const int wave = tid >> 6, lane = tid & 63;
  const int quad = lane >> 4, tn = lane & 15;
  const int bh = blockIdx.y;
  const int qb = (gridDim.x - 1 - blockIdx.x) * 128;  // descending work order
  const int wq = qb + wave * 32;

  const bf16_t* Qb = Qw + (size_t)bh * S_ * HD_;
  const bf16_t* Kb = Kw + (size_t)bh * S_ * HD_;
  const bf16_t* Vb = Vw + (size_t)bh * S_ * HD_;

  const float kScale = 0.125f * 1.44269504088896f;  // 1/sqrt(64) * log2(e)

  // Q fragments (A-layout m=lane&15, k=quad*8+j), scale folded in
  bf16x8 qf[2][2];
#pragma unroll
  for (int mi = 0; mi < 2; mi++)
#pragma unroll
    for (int ks = 0; ks < 2; ks++) {
      bf16x8 v = *(const bf16x8*)&Qb[(size_t)(wq + mi * 16 + tn) * HD_ +
                                     ks * 32 + quad * 8];
#pragma unroll
      for (int j = 0; j < 8; j++) v[j] = (bf16_t)((float)v[j] * kScale);
      qf[mi][ks] = v;
    }

  f32x4 o[2][4] = {};
  const float NEG = -30000.0f;
  float mrow[2][4], lrow[2][4];
#pragma unroll
  for (int mi = 0; mi < 2; mi++)
#pragma unroll
    for (int r = 0; r < 4; r++) {
      mrow[mi][r] = NEG;
      lrow[mi][r] = 0.f;
    }

  const int kt_max = (qb + 127) >> 6;                  // inclusive
  const int s_r = tid >> 2, s_c = (tid & 3) * 16;      // K stage mapping
  const int v_key = tid & 63, v_hb = (tid >> 6) * 16;  // V stage mapping

  for (int kt = 0; kt <= kt_max; kt++) {
    {  // stage K tile [64][hd] and V^T tile [hd][key]
      const bf16_t* kg = Kb + (size_t)(kt * 64 + s_r) * HD_ + s_c;
      *(bf16x8*)&Ks[s_r * 72 + s_c] = *(const bf16x8*)kg;
      *(bf16x8*)&Ks[s_r * 72 + s_c + 8] = *(const bf16x8*)(kg + 8);
      const bf16_t* vg = Vb + (size_t)(kt * 64 + v_key) * HD_ + v_hb;
      bf16x8 v0 = *(const bf16x8*)vg;
      bf16x8 v1 = *(const bf16x8*)(vg + 8);
#pragma unroll
      for (int j = 0; j < 8; j++) {
        Vt[(v_hb + j) * 72 + v_key] = v0[j];
        Vt[(v_hb + 8 + j) * 72 + v_key] = v1[j];
      }
    }
    __syncthreads();

    if (kt * 64 <= wq + 31) {  // wave-uniform; body has no barriers
      f32x4 s[2][4] = {};
#pragma unroll
      for (int ni = 0; ni < 4; ni++)
#pragma unroll
        for (int ks = 0; ks < 2; ks++) {
          bf16x8 kf = *(const bf16x8*)&Ks[(ni * 16 + tn) * 72 + ks * 32 + quad * 8];
#pragma unroll
          for (int mi = 0; mi < 2; mi++)
            s[mi][ni] = __builtin_amdgcn_mfma_f32_16x16x32_bf16(qf[mi][ks], kf,
                                                                s[mi][ni], 0, 0, 0);
        }
      // causal mask only on diagonal tiles (scale already folded into Q)
      if (kt * 64 + 63 > wq) {
#pragma unroll
        for (int mi = 0; mi < 2; mi++)
#pragma unroll
          for (int ni = 0; ni < 4; ni++) {
            int key = kt * 64 + ni * 16 + tn;
#pragma unroll
            for (int r = 0; r < 4; r++) {
              int q = wq + mi * 16 + quad * 4 + r;
              if (key > q) s[mi][ni][r] = NEG;
            }
          }
      }
      // online softmax per row (row spans 16 lanes of a quad)
#pragma unroll
      for (int mi = 0; mi < 2; mi++)
#pragma unroll
        for (int r = 0; r < 4; r++) {
          float mx = fmaxf(fmaxf(s[mi][0][r], s[mi][1][r]),
                           fmaxf(s[mi][2][r], s[mi][3][r]));
#pragma unroll
          for (int off = 1; off < 16; off <<= 1)
            mx = fmaxf(mx, __shfl_xor(mx, off, 64));
          float mnew = fmaxf(mrow[mi][r], mx);
          float alpha = exp2f(mrow[mi][r] - mnew);
          mrow[mi][r] = mnew;
          float rs = 0.f;
#pragma unroll
          for (int ni = 0; ni < 4; ni++) {
            float p = exp2f(s[mi][ni][r] - mnew);
            s[mi][ni][r] = p;
            rs += p;
          }
#pragma unroll
          for (int off = 1; off < 16; off <<= 1) rs += __shfl_xor(rs, off, 64);
          lrow[mi][r] = lrow[mi][r] * alpha + rs;
#pragma unroll
          for (int ni = 0; ni < 4; ni++) o[mi][ni][r] *= alpha;
        }
      // P: C-layout regs -> LDS [q][key], re-read as A-fragments
      bf16_t* Pw = Ps[wave];
#pragma unroll
      for (int mi = 0; mi < 2; mi++)
#pragma unroll
        for (int ni = 0; ni < 4; ni++)
#pragma unroll
          for (int r = 0; r < 4; r++)
            Pw[(mi * 16 + quad * 4 + r) * 72 + ni * 16 + tn] =
                (bf16_t)s[mi][ni][r];
#pragma unroll
      for (int ks = 0; ks < 2; ks++) {
        bf16x8 ap[2];
#pragma unroll
        for (int mi = 0; mi < 2; mi++)
          ap[mi] = *(const bf16x8*)&Pw[(mi * 16 + tn) * 72 + ks * 32 + quad * 8];
#pragma unroll
        for (int ni = 0; ni < 4; ni++) {
          bf16x8 vf = *(const bf16x8*)&Vt[(ni * 16 + tn) * 72 + ks * 32 + quad * 8];
#pragma unroll
          for (int mi = 0; mi < 2; mi++)
            o[mi][ni] = __builtin_amdgcn_mfma_f32_16x16x32_bf16(ap[mi], vf,
                                                                o[mi][ni], 0, 0, 0);
        }
      }
    }
    __syncthreads();
  }

  // normalize + store merged heads [b][s][h*64+hd] (bf16)
  const int b = bh >> 4, h = bh & 15;
#pragma unroll
  for (int mi = 0; mi < 2; mi++)
#pragma unroll
    for (int r = 0; r < 4; r++) {
      int q = wq + mi * 16 + quad * 4 + r;
      float inv = 1.f / fmaxf(lrow[mi][r], 1e-30f);
      bf16_t* dst = Ow + ((size_t)(b * S_ + q) * D_) + h * HD_;
#pragma unroll
      for (int ni = 0; ni < 4; ni++)
        dst[ni * 16 + tn] = (bf16_t)(o[mi][ni][r] * inv);
    }
}

// ---------------------------------------------------------------------------
extern "C" void kernel_launch(void* const* d_in, const int* in_sizes, int n_in,
                              void* d_out, int out_size, void* d_ws,
                              size_t ws_size, hipStream_t stream) {
  const float* hidden = nullptr;
  const float* attn_w = nullptr;
  const float* attn_b = nullptr;
  const float* proj_w = nullptr;
  const float* proj_b = nullptr;
  for (int i = 0; i < n_in; ++i) {
    switch (in_sizes[i]) {
      case 8388608: hidden = (const float*)d_in[i]; break;
      case 3145728: attn_w = (const float*)d_in[i]; break;
      case 3072:    attn_b = (const float*)d_in[i]; break;
      case 1048576: proj_w = (const float*)d_in[i]; break;
      case 1024:    proj_b = (const float*)d_in[i]; break;
      default: break;
    }
  }
  if (!hidden) hidden = (const float*)d_in[0];
  if (!attn_w) attn_w = (const float*)d_in[1];
  if (!attn_b) attn_b = (const float*)d_in[2];
  if (!proj_w) proj_w = (const float*)d_in[3];
  if (!proj_b) proj_b = (const float*)d_in[4];
  float* out = (float*)d_out;  // [4,2048,1024] fp32

  char* ws = (char*)d_ws;
  const size_t AWS_B = (size_t)B_ * S_ * D_ * 2;      // 16,777,216
  const size_t QKV_E = (size_t)B_ * H_ * S_ * HD_;    //  8,388,608 elems

  bf16_t* aws = (bf16_t*)ws;           // [B*S][D]
  bf16_t* wT1 = (bf16_t*)ws;           // [3072][1024] overlay (dead pre-attn)
  bf16_t* qws = (bf16_t*)(ws + AWS_B); // [B,H,S,HD]
  bf16_t* kws = qws + QKV_E;
  bf16_t* vws = kws + QKV_E;
  bf16_t* wT2 = qws;                   // [1024][1024] overlay (post-attn)

  // 1. attn_w [1024][3072] -> wT1 bf16 [3072][1024]
  transpose_cvt<<<dim3(96, 32), dim3(32, 8), 0, stream>>>(attn_w, wT1, 1024, 3072);
  // 2. QKV GEMM: hidden(fp32) x wT1 -> q/k/v scatter
  gemm_bt<<<dim3(24, 64), 256, 0, stream>>>(
      hidden, wT1, attn_b, nullptr, qws, kws, vws, 8192, 3072, 1024, 1, 1, 0);
  // 3. attention -> aws (overwrites wT1: dead)
  attn_kernel<<<dim3(16, 64), 256, 0, stream>>>(qws, kws, vws, aws);
  // 4. proj_w [1024][1024] -> wT2 bf16 (overlays qws: dead after attn)
  transpose_cvt<<<dim3(32, 32), dim3(32, 8), 0, stream>>>(proj_w, wT2, 1024, 1024);
  // 5. proj GEMM: aws(bf16) x wT2 -> out fp32
  gemm_bt<<<dim3(8, 64), 256, 0, stream>>>(
      aws, wT2, proj_b, out, nullptr, nullptr, nullptr, 8192, 1024, 1024, 0, 0, 0);
}